// Round 12
// baseline (492.034 us; speedup 1.0000x reference)
//
#include <hip/hip_runtime.h>
#include <math.h>

#define LOG2E 1.4426950408889634f

#if __has_builtin(__builtin_amdgcn_exp2f)
#define EXP2(x) __builtin_amdgcn_exp2f(x)
#else
#define EXP2(x) exp2f(x)
#endif

constexpr int B_ = 4, N_ = 2048, H_ = 4, D_ = 32, HD_ = 128;
constexpr int BH_ = B_ * H_;          // 16
constexpr int ROWS_ = BH_ * N_;       // 32768
constexpr size_t M_ = (size_t)ROWS_ * D_;  // 1,048,576 floats

typedef float v4f __attribute__((ext_vector_type(4)));
typedef _Float16 h2 __attribute__((ext_vector_type(2)));

// z = |a+b| on packed f16, as u32 bits: v_pk_add_f16 + v_and_b32
static __device__ __forceinline__ unsigned int absadd2(unsigned int a, unsigned int b) {
    h2 s = __builtin_bit_cast(h2, a) + __builtin_bit_cast(h2, b);
    return __builtin_bit_cast(unsigned int, s) & 0x7FFF7FFFu;
}
// acc += dot2(f16x2(a), f16x2(b)) — asm pins acc/ops to ARCH VGPRs
// (R8/R10 disease: builtin fdot2 let the allocator park accumulators in
// AGPRs and shuttle v_accvgpr_read/write around every dot: ~2x instrs).
#define SDOT(acc, a, sb) asm("v_dot2_f32_f16 %0, %1, %2, %0" : "+v"(acc) : "v"(a), "s"(sb))
#define VDOT(acc, a, vb) asm("v_dot2_f32_f16 %0, %1, %2, %0" : "+v"(acc) : "v"(a), "v"(vb))

// x[BN,K] @ Wl/Wr[K,128] + bl/br ->
//   xl   f32 [bh][n][d]      (k_u only)
//   xlh  f16 [bh][n][d]      (score)
//   xrh  f16 [bh][n][d]      (per-lane target rows)
//   xlpT f16 [bh][n/2][d]    (PV: j-pairs per d)
__global__ __launch_bounds__(256) void k_linear(
    const float* __restrict__ x,
    const float* __restrict__ Wl, const float* __restrict__ bl,
    const float* __restrict__ Wr, const float* __restrict__ br,
    float* __restrict__ xl, unsigned short* __restrict__ xlh,
    unsigned short* __restrict__ xrh, unsigned int* __restrict__ xlpT, int K)
{
    __shared__ __align__(16) float xs[32 * 128];
    const int tid = threadIdx.x;
    const int r0 = blockIdx.x * 32;
    const float4* src = (const float4*)(x + (size_t)r0 * K);
    float4* dst = (float4*)xs;
    for (int idx = tid; idx < 8 * K; idx += 256) dst[idx] = src[idx];
    __syncthreads();

    const int c  = tid & 127;
    const int rg = tid >> 7;
    float accl[16], accr[16];
    const float blv = bl[c], brv = br[c];
    #pragma unroll
    for (int r = 0; r < 16; r++) { accl[r] = blv; accr[r] = brv; }
    #pragma unroll 8
    for (int k = 0; k < K; k++) {
        const float wl = Wl[k * HD_ + c];
        const float wr = Wr[k * HD_ + c];
        #pragma unroll
        for (int r = 0; r < 16; r++) {
            const float xv = xs[(rg * 16 + r) * K + k];
            accl[r] = fmaf(xv, wl, accl[r]);
            accr[r] = fmaf(xv, wr, accr[r]);
        }
    }
    const int h = c >> 5, d = c & 31;
    #pragma unroll
    for (int r = 0; r < 16; r++) {
        const int row = r0 + rg * 16 + r;
        const int b = row >> 11, n = row & (N_ - 1);
        const size_t o = (((size_t)(b * H_ + h)) * N_ + n) * D_ + d;
        xl[o] = accl[r];
        xlh[o] = __builtin_bit_cast(unsigned short, (_Float16)accl[r]);
        xrh[o] = __builtin_bit_cast(unsigned short, (_Float16)accr[r]);
    }
    #pragma unroll
    for (int r = 0; r < 16; r += 2) {
        const int row = r0 + rg * 16 + r;
        const int b = row >> 11, n = row & (N_ - 1);
        h2 pr;
        pr.x = (_Float16)accl[r];
        pr.y = (_Float16)accl[r + 1];
        const size_t o = (((size_t)(b * H_ + h)) * (N_ / 2) + (n >> 1)) * D_ + d;
        xlpT[o] = __builtin_bit_cast(unsigned int, pr);
    }
}

// u_j = 0.6*log2e * att_h . xl_j  (target-side term cancels in softmax)
__global__ __launch_bounds__(256) void k_u(
    const float* __restrict__ xl, const float* __restrict__ att,
    float* __restrict__ u)
{
    const int idx = blockIdx.x * 256 + threadIdx.x; // [0, ROWS_)
    const int h = (idx / N_) & (H_ - 1);
    const float4* a4 = (const float4*)(att + h * D_);
    const float4* l4 = (const float4*)(xl + (size_t)idx * D_);
    float su = 0.f;
    #pragma unroll
    for (int q = 0; q < 8; q++) {
        const float4 a = a4[q], lv = l4[q];
        su += a.x * lv.x + a.y * lv.y + a.z * lv.z + a.w * lv.w;
    }
    u[idx] = 0.6f * LOG2E * su;
}

// Per-row sound upper bound on e (log2 domain); also packs tch.
__global__ __launch_bounds__(512) void k_bound(
    const unsigned int* __restrict__ xlh, const unsigned int* __restrict__ xrh,
    const float* __restrict__ u, const float* __restrict__ att,
    float* __restrict__ bound, unsigned int* __restrict__ tch)
{
    __shared__ float redA[16][33];
    __shared__ float redB[16][33];
    __shared__ float clv[32];
    __shared__ float tca[32];
    __shared__ float redu[512];
    const int bh = blockIdx.x, h = bh & (H_ - 1), t = threadIdx.x;

    if (bh < H_ && t < 16) {
        h2 v;
        v.x = (_Float16)(att[bh * D_ + 2 * t]     * (0.4f * LOG2E));
        v.y = (_Float16)(att[bh * D_ + 2 * t + 1] * (0.4f * LOG2E));
        tch[bh * 16 + t] = __builtin_bit_cast(unsigned int, v);
    }
    if (t < 16) {
        _Float16 a = (_Float16)(att[h * D_ + 2 * t]     * (0.4f * LOG2E));
        _Float16 b = (_Float16)(att[h * D_ + 2 * t + 1] * (0.4f * LOG2E));
        tca[2 * t]     = fabsf((float)a);
        tca[2 * t + 1] = fabsf((float)b);
    }
    const unsigned int* xb = xlh + (size_t)bh * N_ * 16;
    const int p = t & 15, rg = t >> 4;
    float m0 = 0.f, m1 = 0.f;
    for (int r = rg; r < N_; r += 32) {
        h2 z = __builtin_bit_cast(h2, xb[r * 16 + p] & 0x7FFF7FFFu);
        m0 = fmaxf(m0, (float)z.x);
        m1 = fmaxf(m1, (float)z.y);
    }
    redA[p][rg] = m0; redB[p][rg] = m1;
    const float* ub = u + (size_t)bh * N_;
    float um = -1e30f;
    for (int r = t; r < N_; r += 512) um = fmaxf(um, ub[r]);
    redu[t] = um;
    __syncthreads();
    if (t < 16) {
        float a = 0.f, b = 0.f;
        for (int g = 0; g < 32; g++) { a = fmaxf(a, redA[t][g]); b = fmaxf(b, redB[t][g]); }
        clv[2 * t] = a; clv[2 * t + 1] = b;
    }
    for (int s = 256; s > 0; s >>= 1) {
        if (t < s) redu[t] = fmaxf(redu[t], redu[t + s]);
        __syncthreads();
    }
    const float umax = redu[0];
    const unsigned int* xrb = xrh + (size_t)bh * N_ * 16;
    for (int r = t; r < N_; r += 512) {
        float s = 0.f;
        #pragma unroll
        for (int k = 0; k < 16; k++) {
            h2 z = __builtin_bit_cast(h2, xrb[r * 16 + k] & 0x7FFF7FFFu);
            s += tca[2 * k] * (clv[2 * k] + (float)z.x)
               + tca[2 * k + 1] * (clv[2 * k + 1] + (float)z.y);
        }
        bound[bh * N_ + r] = umax + s + 0.25f;
    }
}

// Flash GATv2 attention. Lane owns target row i. Fixed-bound softmax ->
// every j independent, no branch, no chain. Inline-asm v_dot2_f32_f16
// pins accumulators to arch VGPRs (no AGPR shuttle). Software-pipelined
// jp loop (ping-pong prefetch of next score rows + u).
// NUMERICS (R11 lesson): numerator AND denominator must use the SAME
// f16-rounded p01 (inconsistent f32 l caused 0.086 absmax); +12 shift
// folded into negb lifts p out of the f16-denormal range (cancels in o/l).
__global__ __launch_bounds__(256)
__attribute__((amdgpu_waves_per_eu(2, 4)))
void k_attn(
    const unsigned int* __restrict__ xlh,   // [bh][n][16] u32 (d-pairs)
    const unsigned int* __restrict__ xlpT,  // [bh][n/2][32] u32 (j-pairs)
    const unsigned int* __restrict__ xrh,
    const float* __restrict__ u, const float* __restrict__ bound,
    const unsigned int* __restrict__ tch,
    float* __restrict__ P, float* __restrict__ lb, int jlen)
{
    const int tid = threadIdx.x, lane = tid & 63, wid = tid >> 6;
    const int t128 = blockIdx.x & 127, part = blockIdx.x >> 7;
    const int bh = t128 >> 3;
    const int h  = bh & (H_ - 1);
    const int row = bh * N_ + (t128 & 7) * 256 + wid * 64 + lane;

    // wave-uniform score coefficients in SGPRs (asm "s" operands)
    unsigned int tcs[16];
    #pragma unroll
    for (int k = 0; k < 16; k++)
        tcs[k] = __builtin_amdgcn_readfirstlane(tch[h * 16 + k]);

    unsigned int xrp[16];
    {
        const uint4* s = (const uint4*)(xrh + (size_t)row * 16);
        const uint4 a = s[0], b = s[1], c = s[2], d = s[3];
        xrp[0]=a.x; xrp[1]=a.y; xrp[2]=a.z; xrp[3]=a.w;
        xrp[4]=b.x; xrp[5]=b.y; xrp[6]=b.z; xrp[7]=b.w;
        xrp[8]=c.x; xrp[9]=c.y; xrp[10]=c.z; xrp[11]=c.w;
        xrp[12]=d.x; xrp[13]=d.y; xrp[14]=d.z; xrp[15]=d.w;
    }
    // +12 shift: p = exp2(e - bound + 12) <= 2^11.75 (f16-safe, non-denormal);
    // scales numerator and denominator identically -> cancels in o/l.
    const float negb = 12.0f - bound[row];
    const unsigned int ONES2 = 0x3C003C00u;   // (1.0h, 1.0h)

    float l = 0.f;
    float o[32];
    #pragma unroll
    for (int k = 0; k < 32; k++) o[k] = 0.f;

    const unsigned int* xlh_b = xlh + (size_t)bh * N_ * 16;
    const unsigned int* xlt_b = xlpT + (size_t)bh * (N_ / 2) * 32;
    const float* u_b = u + (size_t)bh * N_;

    const int jpb = (part * jlen) >> 1, jpe = jpb + (jlen >> 1);

    // ping-pong sets: 2 score rows (8 uint4) + 2 u floats each
#define LOADS(S0, S1, S2, S3, S4, S5, S6, S7, UU0, UU1, JP)                    \
    {                                                                           \
        const uint4* _w = (const uint4*)(xlh_b + (size_t)(2 * (JP)) * 16);     \
        S0 = _w[0]; S1 = _w[1]; S2 = _w[2]; S3 = _w[3];                        \
        S4 = _w[4]; S5 = _w[5]; S6 = _w[6]; S7 = _w[7];                        \
        UU0 = u_b[2 * (JP)]; UU1 = u_b[2 * (JP) + 1];                          \
    }
#define COMPUTE(S0, S1, S2, S3, S4, S5, S6, S7, UU0, UU1, JP)                  \
    {                                                                           \
        const uint4* _vp = (const uint4*)(xlt_b + (size_t)(JP) * 32);          \
        uint4 _v0 = _vp[0], _v1 = _vp[1], _v2 = _vp[2], _v3 = _vp[3];          \
        float _e0 = UU0 + negb, _f0 = 0.f, _e1 = UU1 + negb, _f1 = 0.f;        \
        SDOT(_e0, absadd2(S0.x, xrp[0]),  tcs[0]);                             \
        SDOT(_f0, absadd2(S0.y, xrp[1]),  tcs[1]);                             \
        SDOT(_e0, absadd2(S0.z, xrp[2]),  tcs[2]);                             \
        SDOT(_f0, absadd2(S0.w, xrp[3]),  tcs[3]);                             \
        SDOT(_e0, absadd2(S1.x, xrp[4]),  tcs[4]);                             \
        SDOT(_f0, absadd2(S1.y, xrp[5]),  tcs[5]);                             \
        SDOT(_e0, absadd2(S1.z, xrp[6]),  tcs[6]);                             \
        SDOT(_f0, absadd2(S1.w, xrp[7]),  tcs[7]);                             \
        SDOT(_e0, absadd2(S2.x, xrp[8]),  tcs[8]);                             \
        SDOT(_f0, absadd2(S2.y, xrp[9]),  tcs[9]);                             \
        SDOT(_e0, absadd2(S2.z, xrp[10]), tcs[10]);                            \
        SDOT(_f0, absadd2(S2.w, xrp[11]), tcs[11]);                            \
        SDOT(_e0, absadd2(S3.x, xrp[12]), tcs[12]);                            \
        SDOT(_f0, absadd2(S3.y, xrp[13]), tcs[13]);                            \
        SDOT(_e0, absadd2(S3.z, xrp[14]), tcs[14]);                            \
        SDOT(_f0, absadd2(S3.w, xrp[15]), tcs[15]);                            \
        SDOT(_e1, absadd2(S4.x, xrp[0]),  tcs[0]);                             \
        SDOT(_f1, absadd2(S4.y, xrp[1]),  tcs[1]);                             \
        SDOT(_e1, absadd2(S4.z, xrp[2]),  tcs[2]);                             \
        SDOT(_f1, absadd2(S4.w, xrp[3]),  tcs[3]);                             \
        SDOT(_e1, absadd2(S5.x, xrp[4]),  tcs[4]);                             \
        SDOT(_f1, absadd2(S5.y, xrp[5]),  tcs[5]);                             \
        SDOT(_e1, absadd2(S5.z, xrp[6]),  tcs[6]);                             \
        SDOT(_f1, absadd2(S5.w, xrp[7]),  tcs[7]);                             \
        SDOT(_e1, absadd2(S6.x, xrp[8]),  tcs[8]);                             \
        SDOT(_f1, absadd2(S6.y, xrp[9]),  tcs[9]);                             \
        SDOT(_e1, absadd2(S6.z, xrp[10]), tcs[10]);                            \
        SDOT(_f1, absadd2(S6.w, xrp[11]), tcs[11]);                            \
        SDOT(_e1, absadd2(S7.x, xrp[12]), tcs[12]);                            \
        SDOT(_f1, absadd2(S7.y, xrp[13]), tcs[13]);                            \
        SDOT(_e1, absadd2(S7.z, xrp[14]), tcs[14]);                            \
        SDOT(_f1, absadd2(S7.w, xrp[15]), tcs[15]);                            \
        const float _p0 = EXP2(_e0 + _f0);                                     \
        const float _p1 = EXP2(_e1 + _f1);                                     \
        const unsigned int _p01 = __builtin_bit_cast(unsigned int,             \
            __builtin_amdgcn_cvt_pkrtz(_p0, _p1));                             \
        VDOT(l, _p01, ONES2);                                                  \
        VDOT(o[0],  _p01, _v0.x); VDOT(o[1],  _p01, _v0.y);                    \
        VDOT(o[2],  _p01, _v0.z); VDOT(o[3],  _p01, _v0.w);                    \
        VDOT(o[4],  _p01, _v1.x); VDOT(o[5],  _p01, _v1.y);                    \
        VDOT(o[6],  _p01, _v1.z); VDOT(o[7],  _p01, _v1.w);                    \
        VDOT(o[8],  _p01, _v2.x); VDOT(o[9],  _p01, _v2.y);                    \
        VDOT(o[10], _p01, _v2.z); VDOT(o[11], _p01, _v2.w);                    \
        VDOT(o[12], _p01, _v3.x); VDOT(o[13], _p01, _v3.y);                    \
        VDOT(o[14], _p01, _v3.z); VDOT(o[15], _p01, _v3.w);                    \
        uint4 _v4 = _vp[4], _v5 = _vp[5], _v6 = _vp[6], _v7 = _vp[7];          \
        VDOT(o[16], _p01, _v4.x); VDOT(o[17], _p01, _v4.y);                    \
        VDOT(o[18], _p01, _v4.z); VDOT(o[19], _p01, _v4.w);                    \
        VDOT(o[20], _p01, _v5.x); VDOT(o[21], _p01, _v5.y);                    \
        VDOT(o[22], _p01, _v5.z); VDOT(o[23], _p01, _v5.w);                    \
        VDOT(o[24], _p01, _v6.x); VDOT(o[25], _p01, _v6.y);                    \
        VDOT(o[26], _p01, _v6.z); VDOT(o[27], _p01, _v6.w);                    \
        VDOT(o[28], _p01, _v7.x); VDOT(o[29], _p01, _v7.y);                    \
        VDOT(o[30], _p01, _v7.z); VDOT(o[31], _p01, _v7.w);                    \
    }

    uint4 A0, A1, A2, A3, A4, A5, A6, A7; float AU0, AU1;
    uint4 B0, B1, B2, B3, B4, B5, B6, B7; float BU0, BU1;
    LOADS(A0, A1, A2, A3, A4, A5, A6, A7, AU0, AU1, jpb);
    // jlen/2 is a multiple of 2 for js in {1,2,4,8}; over-fetch at the end
    // lands in the adjacent ws slab (safe, values unused).
    for (int jp = jpb; jp < jpe; jp += 2) {
        LOADS(B0, B1, B2, B3, B4, B5, B6, B7, BU0, BU1, jp + 1);
        COMPUTE(A0, A1, A2, A3, A4, A5, A6, A7, AU0, AU1, jp);
        LOADS(A0, A1, A2, A3, A4, A5, A6, A7, AU0, AU1, jp + 2);
        COMPUTE(B0, B1, B2, B3, B4, B5, B6, B7, BU0, BU1, jp + 1);
    }
#undef LOADS
#undef COMPUTE

    float* Pp = P + (size_t)part * M_ + (size_t)row * D_;
    #pragma unroll
    for (int k = 0; k < 8; k++) {
        v4f w;
        w.x = o[4*k]; w.y = o[4*k+1]; w.z = o[4*k+2]; w.w = o[4*k+3];
        ((v4f*)Pp)[k] = w;
    }
    lb[part * ROWS_ + row] = l;
}

// Fused: merge JS partials (shared bound -> sum(o)/sum(l)) + bias + LN(128)
// (+optional ReLU). One 64-thread block per node row (b,n).
template <int JS>
__global__ __launch_bounds__(64) void k_comb_ln(
    const float* __restrict__ P, const float* __restrict__ lb,
    const float* __restrict__ bias, const float* __restrict__ g,
    const float* __restrict__ bta, float* __restrict__ outp, int do_relu)
{
    const int row = blockIdx.x;                    // b*N+n
    const int b = row >> 11, n = row & (N_ - 1);
    const int t = threadIdx.x;
    const int c0 = t, c1 = t + 64;
    const int bh0 = b * H_ + (c0 >> 5), bh1 = b * H_ + (c1 >> 5);
    const size_t i0 = ((size_t)bh0 * N_ + n) * D_ + (c0 & 31);
    const size_t i1 = ((size_t)bh1 * N_ + n) * D_ + (c1 & 31);
    float a0 = 0.f, a1 = 0.f, L0 = 0.f, L1 = 0.f;
    #pragma unroll
    for (int s = 0; s < JS; s++) {
        a0 += P[(size_t)s * M_ + i0];
        a1 += P[(size_t)s * M_ + i1];
        L0 += lb[s * ROWS_ + bh0 * N_ + n];
        L1 += lb[s * ROWS_ + bh1 * N_ + n];
    }
    const float x0 = a0 / L0 + bias[c0];
    const float x1 = a1 / L1 + bias[c1];
    float s = x0 + x1;
    #pragma unroll
    for (int w = 1; w < 64; w <<= 1) s += __shfl_xor(s, w);
    const float mu = s * (1.f / 128.f);
    const float d0 = x0 - mu, d1 = x1 - mu;
    float q = d0 * d0 + d1 * d1;
    #pragma unroll
    for (int w = 1; w < 64; w <<= 1) q += __shfl_xor(q, w);
    const float rstd = rsqrtf(q * (1.f / 128.f) + 1e-5f);
    float y0 = d0 * rstd * g[c0] + bta[c0];
    float y1 = d1 * rstd * g[c1] + bta[c1];
    if (do_relu) { y0 = fmaxf(y0, 0.f); y1 = fmaxf(y1, 0.f); }
    outp[(size_t)row * HD_ + c0] = y0;
    outp[(size_t)row * HD_ + c1] = y1;
}

extern "C" void kernel_launch(void* const* d_in, const int* in_sizes, int n_in,
                              void* d_out, int out_size, void* d_ws, size_t ws_size,
                              hipStream_t stream) {
    const float* x    = (const float*)d_in[0];
    const float* Wl1  = (const float*)d_in[2];
    const float* bl1  = (const float*)d_in[3];
    const float* Wr1  = (const float*)d_in[4];
    const float* br1  = (const float*)d_in[5];
    const float* att1 = (const float*)d_in[6];
    const float* bias1= (const float*)d_in[7];
    const float* ln1g = (const float*)d_in[8];
    const float* ln1b = (const float*)d_in[9];
    const float* Wl2  = (const float*)d_in[10];
    const float* bl2  = (const float*)d_in[11];
    const float* Wr2  = (const float*)d_in[12];
    const float* br2  = (const float*)d_in[13];
    const float* att2 = (const float*)d_in[14];
    const float* bias2= (const float*)d_in[15];
    const float* ln2g = (const float*)d_in[16];
    const float* ln2b = (const float*)d_in[17];

    float* ws = (float*)d_ws;
    float* xl = ws;                                   // M_
    unsigned short* xlh = (unsigned short*)(xl + M_); // M_ halfs
    unsigned short* xrh = xlh + M_;                   // M_ halfs
    unsigned int* xlpT = (unsigned int*)(xrh + M_);   // M_/2 u32
    float* u     = xl + (size_t)(2.5 * M_);           // ROWS_
    float* bound = u + ROWS_;                         // ROWS_
    unsigned int* tch = (unsigned int*)(bound + ROWS_); // 64 u32

    // j-split: largest fitting. floats = 2.5M + 2R + 64 + js*(M+R) + M (h slab)
    int js = 1;
    for (int cand = 8; cand >= 1; cand >>= 1) {
        const size_t need = ((size_t)(3.5 * M_) + 2 * ROWS_ + 64
                             + (size_t)cand * (M_ + ROWS_)) * sizeof(float);
        if (ws_size >= need) { js = cand; break; }
    }
    const int jlen = N_ / js;

    float* P  = (float*)(tch + 64);        // js * M_
    float* lb = P + (size_t)js * M_;       // js * ROWS_
    float* h  = lb + (size_t)js * ROWS_;   // M_ (dedicated slab)
    float* outf = (float*)d_out;

    const int BN = B_ * N_;                // 8192
    // ---- layer 1 ----
    k_linear<<<BN / 32, 256, 0, stream>>>(x, Wl1, bl1, Wr1, br1, xl, xlh, xrh, xlpT, 32);
    k_u<<<ROWS_ / 256, 256, 0, stream>>>(xl, att1, u);
    k_bound<<<BH_, 512, 0, stream>>>((const unsigned int*)xlh, (const unsigned int*)xrh,
                                     u, att1, bound, tch);
    k_attn<<<128 * js, 256, 0, stream>>>((const unsigned int*)xlh, xlpT,
                                         (const unsigned int*)xrh, u, bound, tch, P, lb, jlen);
    if      (js == 8) k_comb_ln<8><<<BN, 64, 0, stream>>>(P, lb, bias1, ln1g, ln1b, h, 1);
    else if (js == 4) k_comb_ln<4><<<BN, 64, 0, stream>>>(P, lb, bias1, ln1g, ln1b, h, 1);
    else if (js == 2) k_comb_ln<2><<<BN, 64, 0, stream>>>(P, lb, bias1, ln1g, ln1b, h, 1);
    else              k_comb_ln<1><<<BN, 64, 0, stream>>>(P, lb, bias1, ln1g, ln1b, h, 1);
    // ---- layer 2 ----
    k_linear<<<BN / 32, 256, 0, stream>>>(h, Wl2, bl2, Wr2, br2, xl, xlh, xrh, xlpT, 128);
    k_u<<<ROWS_ / 256, 256, 0, stream>>>(xl, att2, u);
    k_bound<<<BH_, 512, 0, stream>>>((const unsigned int*)xlh, (const unsigned int*)xrh,
                                     u, att2, bound, tch);
    k_attn<<<128 * js, 256, 0, stream>>>((const unsigned int*)xlh, xlpT,
                                         (const unsigned int*)xrh, u, bound, tch, P, lb, jlen);
    if      (js == 8) k_comb_ln<8><<<BN, 64, 0, stream>>>(P, lb, bias2, ln2g, ln2b, outf, 0);
    else if (js == 4) k_comb_ln<4><<<BN, 64, 0, stream>>>(P, lb, bias2, ln2g, ln2b, outf, 0);
    else if (js == 2) k_comb_ln<2><<<BN, 64, 0, stream>>>(P, lb, bias2, ln2g, ln2b, outf, 0);
    else              k_comb_ln<1><<<BN, 64, 0, stream>>>(P, lb, bias2, ln2g, ln2b, outf, 0);
}

// Round 13
// 429.685 us; speedup vs baseline: 1.1451x; 1.1451x over previous
//
#include <hip/hip_runtime.h>
#include <math.h>

#define LOG2E 1.4426950408889634f

#if __has_builtin(__builtin_amdgcn_exp2f)
#define EXP2(x) __builtin_amdgcn_exp2f(x)
#else
#define EXP2(x) exp2f(x)
#endif

constexpr int B_ = 4, N_ = 2048, H_ = 4, D_ = 32, HD_ = 128;
constexpr int BH_ = B_ * H_;          // 16
constexpr int ROWS_ = BH_ * N_;       // 32768
constexpr size_t M_ = (size_t)ROWS_ * D_;  // 1,048,576 floats

typedef float v4f __attribute__((ext_vector_type(4)));
typedef _Float16 h2 __attribute__((ext_vector_type(2)));

// z = |a+b| on packed f16, as u32 bits: v_pk_add_f16 + v_and_b32
static __device__ __forceinline__ unsigned int absadd2(unsigned int a, unsigned int b) {
    h2 s = __builtin_bit_cast(h2, a) + __builtin_bit_cast(h2, b);
    return __builtin_bit_cast(unsigned int, s) & 0x7FFF7FFFu;
}
// acc += dot2(f16x2(a), f16x2(b)) — asm guarantees v_dot2 formation and pins
// operands to arch VGPRs at the use site.
#define SDOT(acc, a, sb) asm("v_dot2_f32_f16 %0, %1, %2, %0" : "+v"(acc) : "v"(a), "s"(sb))
#define VDOT(acc, a, vb) asm("v_dot2_f32_f16 %0, %1, %2, %0" : "+v"(acc) : "v"(a), "v"(vb))

// x[BN,K] @ Wl/Wr[K,128] + bl/br ->
//   xl   f32 [bh][n][d]      (k_u only)
//   xlh  f16 [bh][n][d]      (score)
//   xrh  f16 [bh][n][d]      (per-lane target rows)
//   xlpT f16 [bh][n/2][d]    (PV: j-pairs per d)
__global__ __launch_bounds__(256) void k_linear(
    const float* __restrict__ x,
    const float* __restrict__ Wl, const float* __restrict__ bl,
    const float* __restrict__ Wr, const float* __restrict__ br,
    float* __restrict__ xl, unsigned short* __restrict__ xlh,
    unsigned short* __restrict__ xrh, unsigned int* __restrict__ xlpT, int K)
{
    __shared__ __align__(16) float xs[32 * 128];
    const int tid = threadIdx.x;
    const int r0 = blockIdx.x * 32;
    const float4* src = (const float4*)(x + (size_t)r0 * K);
    float4* dst = (float4*)xs;
    for (int idx = tid; idx < 8 * K; idx += 256) dst[idx] = src[idx];
    __syncthreads();

    const int c  = tid & 127;
    const int rg = tid >> 7;
    float accl[16], accr[16];
    const float blv = bl[c], brv = br[c];
    #pragma unroll
    for (int r = 0; r < 16; r++) { accl[r] = blv; accr[r] = brv; }
    #pragma unroll 8
    for (int k = 0; k < K; k++) {
        const float wl = Wl[k * HD_ + c];
        const float wr = Wr[k * HD_ + c];
        #pragma unroll
        for (int r = 0; r < 16; r++) {
            const float xv = xs[(rg * 16 + r) * K + k];
            accl[r] = fmaf(xv, wl, accl[r]);
            accr[r] = fmaf(xv, wr, accr[r]);
        }
    }
    const int h = c >> 5, d = c & 31;
    #pragma unroll
    for (int r = 0; r < 16; r++) {
        const int row = r0 + rg * 16 + r;
        const int b = row >> 11, n = row & (N_ - 1);
        const size_t o = (((size_t)(b * H_ + h)) * N_ + n) * D_ + d;
        xl[o] = accl[r];
        xlh[o] = __builtin_bit_cast(unsigned short, (_Float16)accl[r]);
        xrh[o] = __builtin_bit_cast(unsigned short, (_Float16)accr[r]);
    }
    #pragma unroll
    for (int r = 0; r < 16; r += 2) {
        const int row = r0 + rg * 16 + r;
        const int b = row >> 11, n = row & (N_ - 1);
        h2 pr;
        pr.x = (_Float16)accl[r];
        pr.y = (_Float16)accl[r + 1];
        const size_t o = (((size_t)(b * H_ + h)) * (N_ / 2) + (n >> 1)) * D_ + d;
        xlpT[o] = __builtin_bit_cast(unsigned int, pr);
    }
}

// u_j = 0.6*log2e * att_h . xl_j  (target-side term cancels in softmax)
__global__ __launch_bounds__(256) void k_u(
    const float* __restrict__ xl, const float* __restrict__ att,
    float* __restrict__ u)
{
    const int idx = blockIdx.x * 256 + threadIdx.x; // [0, ROWS_)
    const int h = (idx / N_) & (H_ - 1);
    const float4* a4 = (const float4*)(att + h * D_);
    const float4* l4 = (const float4*)(xl + (size_t)idx * D_);
    float su = 0.f;
    #pragma unroll
    for (int q = 0; q < 8; q++) {
        const float4 a = a4[q], lv = l4[q];
        su += a.x * lv.x + a.y * lv.y + a.z * lv.z + a.w * lv.w;
    }
    u[idx] = 0.6f * LOG2E * su;
}

// Per-row sound upper bound on e (log2 domain); also packs tch.
__global__ __launch_bounds__(512) void k_bound(
    const unsigned int* __restrict__ xlh, const unsigned int* __restrict__ xrh,
    const float* __restrict__ u, const float* __restrict__ att,
    float* __restrict__ bound, unsigned int* __restrict__ tch)
{
    __shared__ float redA[16][33];
    __shared__ float redB[16][33];
    __shared__ float clv[32];
    __shared__ float tca[32];
    __shared__ float redu[512];
    const int bh = blockIdx.x, h = bh & (H_ - 1), t = threadIdx.x;

    if (bh < H_ && t < 16) {
        h2 v;
        v.x = (_Float16)(att[bh * D_ + 2 * t]     * (0.4f * LOG2E));
        v.y = (_Float16)(att[bh * D_ + 2 * t + 1] * (0.4f * LOG2E));
        tch[bh * 16 + t] = __builtin_bit_cast(unsigned int, v);
    }
    if (t < 16) {
        _Float16 a = (_Float16)(att[h * D_ + 2 * t]     * (0.4f * LOG2E));
        _Float16 b = (_Float16)(att[h * D_ + 2 * t + 1] * (0.4f * LOG2E));
        tca[2 * t]     = fabsf((float)a);
        tca[2 * t + 1] = fabsf((float)b);
    }
    const unsigned int* xb = xlh + (size_t)bh * N_ * 16;
    const int p = t & 15, rg = t >> 4;
    float m0 = 0.f, m1 = 0.f;
    for (int r = rg; r < N_; r += 32) {
        h2 z = __builtin_bit_cast(h2, xb[r * 16 + p] & 0x7FFF7FFFu);
        m0 = fmaxf(m0, (float)z.x);
        m1 = fmaxf(m1, (float)z.y);
    }
    redA[p][rg] = m0; redB[p][rg] = m1;
    const float* ub = u + (size_t)bh * N_;
    float um = -1e30f;
    for (int r = t; r < N_; r += 512) um = fmaxf(um, ub[r]);
    redu[t] = um;
    __syncthreads();
    if (t < 16) {
        float a = 0.f, b = 0.f;
        for (int g = 0; g < 32; g++) { a = fmaxf(a, redA[t][g]); b = fmaxf(b, redB[t][g]); }
        clv[2 * t] = a; clv[2 * t + 1] = b;
    }
    for (int s = 256; s > 0; s >>= 1) {
        if (t < s) redu[t] = fmaxf(redu[t], redu[t + s]);
        __syncthreads();
    }
    const float umax = redu[0];
    const unsigned int* xrb = xrh + (size_t)bh * N_ * 16;
    for (int r = t; r < N_; r += 512) {
        float s = 0.f;
        #pragma unroll
        for (int k = 0; k < 16; k++) {
            h2 z = __builtin_bit_cast(h2, xrb[r * 16 + k] & 0x7FFF7FFFu);
            s += tca[2 * k] * (clv[2 * k] + (float)z.x)
               + tca[2 * k + 1] * (clv[2 * k + 1] + (float)z.y);
        }
        bound[bh * N_ + r] = umax + s + 0.25f;
    }
}

// Flash GATv2 attention. Lane owns target row i; all 4 waves of a block share
// the same (bh, j-range), so j-tiles are staged in LDS cooperatively (33 KB:
// score rows 16K + PV j-pairs 16K + u 1K) and read as wave-uniform broadcasts.
// LDS ALSO sets the compiler's occupancy estimate to 4 blocks/CU -> VGPR
// budget 128 > ~90 live set -> no AGPR shuttling (R8-R12 plateau: no-LDS
// kernels get a 64-VGPR budget and round-trip accumulators through AGPRs).
// Fixed-bound softmax -> j's independent; numerics = R12 (passed).
__global__ __launch_bounds__(256) void k_attn(
    const unsigned int* __restrict__ xlh,   // [bh][n][16] u32 (d-pairs)
    const unsigned int* __restrict__ xlpT,  // [bh][n/2][32] u32 (j-pairs)
    const unsigned int* __restrict__ xrh,
    const float* __restrict__ u, const float* __restrict__ bound,
    const unsigned int* __restrict__ tch,
    float* __restrict__ P, float* __restrict__ lb, int jlen)
{
    __shared__ __align__(16) uint4 s_xlh[1024];   // 256 j-rows x 4 uint4
    __shared__ __align__(16) uint4 s_xlt[1024];   // 128 jp x 8 uint4
    __shared__ float s_u[256];
    const int tid = threadIdx.x;
    const int t128 = blockIdx.x & 127, part = blockIdx.x >> 7;
    const int bh = t128 >> 3;
    const int h  = bh & (H_ - 1);
    const int row = bh * N_ + (t128 & 7) * 256 + tid;

    // wave-uniform score coefficients in SGPRs
    unsigned int tcs[16];
    #pragma unroll
    for (int k = 0; k < 16; k++)
        tcs[k] = __builtin_amdgcn_readfirstlane(tch[h * 16 + k]);

    unsigned int xrp[16];
    {
        const uint4* s = (const uint4*)(xrh + (size_t)row * 16);
        const uint4 a = s[0], b = s[1], c = s[2], d = s[3];
        xrp[0]=a.x; xrp[1]=a.y; xrp[2]=a.z; xrp[3]=a.w;
        xrp[4]=b.x; xrp[5]=b.y; xrp[6]=b.z; xrp[7]=b.w;
        xrp[8]=c.x; xrp[9]=c.y; xrp[10]=c.z; xrp[11]=c.w;
        xrp[12]=d.x; xrp[13]=d.y; xrp[14]=d.z; xrp[15]=d.w;
    }
    // +12 shift keeps p in f16 normal range; cancels in o/l (R12 numerics).
    const float negb = 12.0f - bound[row];
    const unsigned int ONES2 = 0x3C003C00u;   // (1.0h, 1.0h)

    float l = 0.f;
    float o[32];
    #pragma unroll
    for (int k = 0; k < 32; k++) o[k] = 0.f;

    const uint4* gx = (const uint4*)(xlh + (size_t)bh * N_ * 16);        // 4/row
    const uint4* gv = (const uint4*)(xlpT + (size_t)bh * (N_ / 2) * 32); // 8/jp
    const float* u_b = u + (size_t)bh * N_;

    const int jbeg = part * jlen;
    for (int jt = 0; jt < jlen; jt += 256) {
        if (jt) __syncthreads();                 // previous tile fully consumed
        const int j0 = jbeg + jt;
        #pragma unroll
        for (int k = 0; k < 4; k++)
            s_xlh[tid + 256 * k] = gx[(size_t)j0 * 4 + tid + 256 * k];
        #pragma unroll
        for (int k = 0; k < 4; k++)
            s_xlt[tid + 256 * k] = gv[(size_t)(j0 >> 1) * 8 + tid + 256 * k];
        s_u[tid] = u_b[j0 + tid];
        __syncthreads();

        for (int ljp = 0; ljp < 128; ljp++) {
            const uint4 S0 = s_xlh[8 * ljp + 0], S1 = s_xlh[8 * ljp + 1];
            const uint4 S2 = s_xlh[8 * ljp + 2], S3 = s_xlh[8 * ljp + 3];
            const uint4 S4 = s_xlh[8 * ljp + 4], S5 = s_xlh[8 * ljp + 5];
            const uint4 S6 = s_xlh[8 * ljp + 6], S7 = s_xlh[8 * ljp + 7];
            float e0 = s_u[2 * ljp] + negb, f0 = 0.f;
            float e1 = s_u[2 * ljp + 1] + negb, f1 = 0.f;
            SDOT(e0, absadd2(S0.x, xrp[0]),  tcs[0]);
            SDOT(f0, absadd2(S0.y, xrp[1]),  tcs[1]);
            SDOT(e0, absadd2(S0.z, xrp[2]),  tcs[2]);
            SDOT(f0, absadd2(S0.w, xrp[3]),  tcs[3]);
            SDOT(e0, absadd2(S1.x, xrp[4]),  tcs[4]);
            SDOT(f0, absadd2(S1.y, xrp[5]),  tcs[5]);
            SDOT(e0, absadd2(S1.z, xrp[6]),  tcs[6]);
            SDOT(f0, absadd2(S1.w, xrp[7]),  tcs[7]);
            SDOT(e0, absadd2(S2.x, xrp[8]),  tcs[8]);
            SDOT(f0, absadd2(S2.y, xrp[9]),  tcs[9]);
            SDOT(e0, absadd2(S2.z, xrp[10]), tcs[10]);
            SDOT(f0, absadd2(S2.w, xrp[11]), tcs[11]);
            SDOT(e0, absadd2(S3.x, xrp[12]), tcs[12]);
            SDOT(f0, absadd2(S3.y, xrp[13]), tcs[13]);
            SDOT(e0, absadd2(S3.z, xrp[14]), tcs[14]);
            SDOT(f0, absadd2(S3.w, xrp[15]), tcs[15]);
            SDOT(e1, absadd2(S4.x, xrp[0]),  tcs[0]);
            SDOT(f1, absadd2(S4.y, xrp[1]),  tcs[1]);
            SDOT(e1, absadd2(S4.z, xrp[2]),  tcs[2]);
            SDOT(f1, absadd2(S4.w, xrp[3]),  tcs[3]);
            SDOT(e1, absadd2(S5.x, xrp[4]),  tcs[4]);
            SDOT(f1, absadd2(S5.y, xrp[5]),  tcs[5]);
            SDOT(e1, absadd2(S5.z, xrp[6]),  tcs[6]);
            SDOT(f1, absadd2(S5.w, xrp[7]),  tcs[7]);
            SDOT(e1, absadd2(S6.x, xrp[8]),  tcs[8]);
            SDOT(f1, absadd2(S6.y, xrp[9]),  tcs[9]);
            SDOT(e1, absadd2(S6.z, xrp[10]), tcs[10]);
            SDOT(f1, absadd2(S6.w, xrp[11]), tcs[11]);
            SDOT(e1, absadd2(S7.x, xrp[12]), tcs[12]);
            SDOT(f1, absadd2(S7.y, xrp[13]), tcs[13]);
            SDOT(e1, absadd2(S7.z, xrp[14]), tcs[14]);
            SDOT(f1, absadd2(S7.w, xrp[15]), tcs[15]);
            const float p0 = EXP2(e0 + f0);
            const float p1 = EXP2(e1 + f1);
            const unsigned int p01 = __builtin_bit_cast(unsigned int,
                __builtin_amdgcn_cvt_pkrtz(p0, p1));
            VDOT(l, p01, ONES2);
            const uint4 V0 = s_xlt[8 * ljp + 0], V1 = s_xlt[8 * ljp + 1];
            const uint4 V2 = s_xlt[8 * ljp + 2], V3 = s_xlt[8 * ljp + 3];
            VDOT(o[0],  p01, V0.x); VDOT(o[1],  p01, V0.y);
            VDOT(o[2],  p01, V0.z); VDOT(o[3],  p01, V0.w);
            VDOT(o[4],  p01, V1.x); VDOT(o[5],  p01, V1.y);
            VDOT(o[6],  p01, V1.z); VDOT(o[7],  p01, V1.w);
            VDOT(o[8],  p01, V2.x); VDOT(o[9],  p01, V2.y);
            VDOT(o[10], p01, V2.z); VDOT(o[11], p01, V2.w);
            VDOT(o[12], p01, V3.x); VDOT(o[13], p01, V3.y);
            VDOT(o[14], p01, V3.z); VDOT(o[15], p01, V3.w);
            const uint4 V4 = s_xlt[8 * ljp + 4], V5 = s_xlt[8 * ljp + 5];
            const uint4 V6 = s_xlt[8 * ljp + 6], V7 = s_xlt[8 * ljp + 7];
            VDOT(o[16], p01, V4.x); VDOT(o[17], p01, V4.y);
            VDOT(o[18], p01, V4.z); VDOT(o[19], p01, V4.w);
            VDOT(o[20], p01, V5.x); VDOT(o[21], p01, V5.y);
            VDOT(o[22], p01, V5.z); VDOT(o[23], p01, V5.w);
            VDOT(o[24], p01, V6.x); VDOT(o[25], p01, V6.y);
            VDOT(o[26], p01, V6.z); VDOT(o[27], p01, V6.w);
            VDOT(o[28], p01, V7.x); VDOT(o[29], p01, V7.y);
            VDOT(o[30], p01, V7.z); VDOT(o[31], p01, V7.w);
        }
    }

    float* Pp = P + (size_t)part * M_ + (size_t)row * D_;
    #pragma unroll
    for (int k = 0; k < 8; k++) {
        v4f w;
        w.x = o[4*k]; w.y = o[4*k+1]; w.z = o[4*k+2]; w.w = o[4*k+3];
        ((v4f*)Pp)[k] = w;
    }
    lb[part * ROWS_ + row] = l;
}

// Fused: merge JS partials (shared bound -> sum(o)/sum(l)) + bias + LN(128)
// (+optional ReLU). One 64-thread block per node row (b,n).
template <int JS>
__global__ __launch_bounds__(64) void k_comb_ln(
    const float* __restrict__ P, const float* __restrict__ lb,
    const float* __restrict__ bias, const float* __restrict__ g,
    const float* __restrict__ bta, float* __restrict__ outp, int do_relu)
{
    const int row = blockIdx.x;                    // b*N+n
    const int b = row >> 11, n = row & (N_ - 1);
    const int t = threadIdx.x;
    const int c0 = t, c1 = t + 64;
    const int bh0 = b * H_ + (c0 >> 5), bh1 = b * H_ + (c1 >> 5);
    const size_t i0 = ((size_t)bh0 * N_ + n) * D_ + (c0 & 31);
    const size_t i1 = ((size_t)bh1 * N_ + n) * D_ + (c1 & 31);
    float a0 = 0.f, a1 = 0.f, L0 = 0.f, L1 = 0.f;
    #pragma unroll
    for (int s = 0; s < JS; s++) {
        a0 += P[(size_t)s * M_ + i0];
        a1 += P[(size_t)s * M_ + i1];
        L0 += lb[s * ROWS_ + bh0 * N_ + n];
        L1 += lb[s * ROWS_ + bh1 * N_ + n];
    }
    const float x0 = a0 / L0 + bias[c0];
    const float x1 = a1 / L1 + bias[c1];
    float s = x0 + x1;
    #pragma unroll
    for (int w = 1; w < 64; w <<= 1) s += __shfl_xor(s, w);
    const float mu = s * (1.f / 128.f);
    const float d0 = x0 - mu, d1 = x1 - mu;
    float q = d0 * d0 + d1 * d1;
    #pragma unroll
    for (int w = 1; w < 64; w <<= 1) q += __shfl_xor(q, w);
    const float rstd = rsqrtf(q * (1.f / 128.f) + 1e-5f);
    float y0 = d0 * rstd * g[c0] + bta[c0];
    float y1 = d1 * rstd * g[c1] + bta[c1];
    if (do_relu) { y0 = fmaxf(y0, 0.f); y1 = fmaxf(y1, 0.f); }
    outp[(size_t)row * HD_ + c0] = y0;
    outp[(size_t)row * HD_ + c1] = y1;
}

extern "C" void kernel_launch(void* const* d_in, const int* in_sizes, int n_in,
                              void* d_out, int out_size, void* d_ws, size_t ws_size,
                              hipStream_t stream) {
    const float* x    = (const float*)d_in[0];
    const float* Wl1  = (const float*)d_in[2];
    const float* bl1  = (const float*)d_in[3];
    const float* Wr1  = (const float*)d_in[4];
    const float* br1  = (const float*)d_in[5];
    const float* att1 = (const float*)d_in[6];
    const float* bias1= (const float*)d_in[7];
    const float* ln1g = (const float*)d_in[8];
    const float* ln1b = (const float*)d_in[9];
    const float* Wl2  = (const float*)d_in[10];
    const float* bl2  = (const float*)d_in[11];
    const float* Wr2  = (const float*)d_in[12];
    const float* br2  = (const float*)d_in[13];
    const float* att2 = (const float*)d_in[14];
    const float* bias2= (const float*)d_in[15];
    const float* ln2g = (const float*)d_in[16];
    const float* ln2b = (const float*)d_in[17];

    float* ws = (float*)d_ws;
    float* xl = ws;                                   // M_
    unsigned short* xlh = (unsigned short*)(xl + M_); // M_ halfs
    unsigned short* xrh = xlh + M_;                   // M_ halfs
    unsigned int* xlpT = (unsigned int*)(xrh + M_);   // M_/2 u32
    float* u     = xl + (size_t)(2.5 * M_);           // ROWS_
    float* bound = u + ROWS_;                         // ROWS_
    unsigned int* tch = (unsigned int*)(bound + ROWS_); // 64 u32

    // j-split: largest fitting. floats = 2.5M + 2R + 64 + js*(M+R) + M (h slab)
    int js = 1;
    for (int cand = 8; cand >= 1; cand >>= 1) {
        const size_t need = ((size_t)(3.5 * M_) + 2 * ROWS_ + 64
                             + (size_t)cand * (M_ + ROWS_)) * sizeof(float);
        if (ws_size >= need) { js = cand; break; }
    }
    const int jlen = N_ / js;

    float* P  = (float*)(tch + 64);        // js * M_
    float* lb = P + (size_t)js * M_;       // js * ROWS_
    float* h  = lb + (size_t)js * ROWS_;   // M_ (dedicated slab)
    float* outf = (float*)d_out;

    const int BN = B_ * N_;                // 8192
    // ---- layer 1 ----
    k_linear<<<BN / 32, 256, 0, stream>>>(x, Wl1, bl1, Wr1, br1, xl, xlh, xrh, xlpT, 32);
    k_u<<<ROWS_ / 256, 256, 0, stream>>>(xl, att1, u);
    k_bound<<<BH_, 512, 0, stream>>>((const unsigned int*)xlh, (const unsigned int*)xrh,
                                     u, att1, bound, tch);
    k_attn<<<128 * js, 256, 0, stream>>>((const unsigned int*)xlh, xlpT,
                                         (const unsigned int*)xrh, u, bound, tch, P, lb, jlen);
    if      (js == 8) k_comb_ln<8><<<BN, 64, 0, stream>>>(P, lb, bias1, ln1g, ln1b, h, 1);
    else if (js == 4) k_comb_ln<4><<<BN, 64, 0, stream>>>(P, lb, bias1, ln1g, ln1b, h, 1);
    else if (js == 2) k_comb_ln<2><<<BN, 64, 0, stream>>>(P, lb, bias1, ln1g, ln1b, h, 1);
    else              k_comb_ln<1><<<BN, 64, 0, stream>>>(P, lb, bias1, ln1g, ln1b, h, 1);
    // ---- layer 2 ----
    k_linear<<<BN / 32, 256, 0, stream>>>(h, Wl2, bl2, Wr2, br2, xl, xlh, xrh, xlpT, 128);
    k_u<<<ROWS_ / 256, 256, 0, stream>>>(xl, att2, u);
    k_bound<<<BH_, 512, 0, stream>>>((const unsigned int*)xlh, (const unsigned int*)xrh,
                                     u, att2, bound, tch);
    k_attn<<<128 * js, 256, 0, stream>>>((const unsigned int*)xlh, xlpT,
                                         (const unsigned int*)xrh, u, bound, tch, P, lb, jlen);
    if      (js == 8) k_comb_ln<8><<<BN, 64, 0, stream>>>(P, lb, bias2, ln2g, ln2b, outf, 0);
    else if (js == 4) k_comb_ln<4><<<BN, 64, 0, stream>>>(P, lb, bias2, ln2g, ln2b, outf, 0);
    else if (js == 2) k_comb_ln<2><<<BN, 64, 0, stream>>>(P, lb, bias2, ln2g, ln2b, outf, 0);
    else              k_comb_ln<1><<<BN, 64, 0, stream>>>(P, lb, bias2, ln2g, ln2b, outf, 0);
}

// Round 15
// 411.712 us; speedup vs baseline: 1.1951x; 1.0437x over previous
//
#include <hip/hip_runtime.h>
#include <math.h>

#define LOG2E 1.4426950408889634f

#if __has_builtin(__builtin_amdgcn_exp2f)
#define EXP2(x) __builtin_amdgcn_exp2f(x)
#else
#define EXP2(x) exp2f(x)
#endif

constexpr int B_ = 4, N_ = 2048, H_ = 4, D_ = 32, HD_ = 128;
constexpr int BH_ = B_ * H_;          // 16
constexpr int ROWS_ = BH_ * N_;       // 32768
constexpr size_t M_ = (size_t)ROWS_ * D_;  // 1,048,576 floats

typedef float v4f __attribute__((ext_vector_type(4)));
typedef _Float16 h2 __attribute__((ext_vector_type(2)));

// x[BN,K] @ Wl/Wr[K,128] + bl/br ->
//   xl   f32 [bh][n][d]      (k_u only)
//   xlh  f16 [bh][n][d]      (score)
//   xrh  f16 [bh][n][d]      (per-lane target rows)
//   xlpT f16 [bh][n/2][d]    (PV: j-pairs per d)
__global__ __launch_bounds__(256) void k_linear(
    const float* __restrict__ x,
    const float* __restrict__ Wl, const float* __restrict__ bl,
    const float* __restrict__ Wr, const float* __restrict__ br,
    float* __restrict__ xl, unsigned short* __restrict__ xlh,
    unsigned short* __restrict__ xrh, unsigned int* __restrict__ xlpT, int K)
{
    __shared__ __align__(16) float xs[32 * 128];
    const int tid = threadIdx.x;
    const int r0 = blockIdx.x * 32;
    const float4* src = (const float4*)(x + (size_t)r0 * K);
    float4* dst = (float4*)xs;
    for (int idx = tid; idx < 8 * K; idx += 256) dst[idx] = src[idx];
    __syncthreads();

    const int c  = tid & 127;
    const int rg = tid >> 7;
    float accl[16], accr[16];
    const float blv = bl[c], brv = br[c];
    #pragma unroll
    for (int r = 0; r < 16; r++) { accl[r] = blv; accr[r] = brv; }
    #pragma unroll 8
    for (int k = 0; k < K; k++) {
        const float wl = Wl[k * HD_ + c];
        const float wr = Wr[k * HD_ + c];
        #pragma unroll
        for (int r = 0; r < 16; r++) {
            const float xv = xs[(rg * 16 + r) * K + k];
            accl[r] = fmaf(xv, wl, accl[r]);
            accr[r] = fmaf(xv, wr, accr[r]);
        }
    }
    const int h = c >> 5, d = c & 31;
    #pragma unroll
    for (int r = 0; r < 16; r++) {
        const int row = r0 + rg * 16 + r;
        const int b = row >> 11, n = row & (N_ - 1);
        const size_t o = (((size_t)(b * H_ + h)) * N_ + n) * D_ + d;
        xl[o] = accl[r];
        xlh[o] = __builtin_bit_cast(unsigned short, (_Float16)accl[r]);
        xrh[o] = __builtin_bit_cast(unsigned short, (_Float16)accr[r]);
    }
    #pragma unroll
    for (int r = 0; r < 16; r += 2) {
        const int row = r0 + rg * 16 + r;
        const int b = row >> 11, n = row & (N_ - 1);
        h2 pr;
        pr.x = (_Float16)accl[r];
        pr.y = (_Float16)accl[r + 1];
        const size_t o = (((size_t)(b * H_ + h)) * (N_ / 2) + (n >> 1)) * D_ + d;
        xlpT[o] = __builtin_bit_cast(unsigned int, pr);
    }
}

// u_j = 0.6*log2e * att_h . xl_j  (target-side term cancels in softmax)
__global__ __launch_bounds__(256) void k_u(
    const float* __restrict__ xl, const float* __restrict__ att,
    float* __restrict__ u)
{
    const int idx = blockIdx.x * 256 + threadIdx.x; // [0, ROWS_)
    const int h = (idx / N_) & (H_ - 1);
    const float4* a4 = (const float4*)(att + h * D_);
    const float4* l4 = (const float4*)(xl + (size_t)idx * D_);
    float su = 0.f;
    #pragma unroll
    for (int q = 0; q < 8; q++) {
        const float4 a = a4[q], lv = l4[q];
        su += a.x * lv.x + a.y * lv.y + a.z * lv.z + a.w * lv.w;
    }
    u[idx] = 0.6f * LOG2E * su;
}

// Per-row sound upper bound on e (log2 domain); also packs tch.
__global__ __launch_bounds__(512) void k_bound(
    const unsigned int* __restrict__ xlh, const unsigned int* __restrict__ xrh,
    const float* __restrict__ u, const float* __restrict__ att,
    float* __restrict__ bound, unsigned int* __restrict__ tch)
{
    __shared__ float redA[16][33];
    __shared__ float redB[16][33];
    __shared__ float clv[32];
    __shared__ float tca[32];
    __shared__ float redu[512];
    const int bh = blockIdx.x, h = bh & (H_ - 1), t = threadIdx.x;

    if (bh < H_ && t < 16) {
        h2 v;
        v.x = (_Float16)(att[bh * D_ + 2 * t]     * (0.4f * LOG2E));
        v.y = (_Float16)(att[bh * D_ + 2 * t + 1] * (0.4f * LOG2E));
        tch[bh * 16 + t] = __builtin_bit_cast(unsigned int, v);
    }
    if (t < 16) {
        _Float16 a = (_Float16)(att[h * D_ + 2 * t]     * (0.4f * LOG2E));
        _Float16 b = (_Float16)(att[h * D_ + 2 * t + 1] * (0.4f * LOG2E));
        tca[2 * t]     = fabsf((float)a);
        tca[2 * t + 1] = fabsf((float)b);
    }
    const unsigned int* xb = xlh + (size_t)bh * N_ * 16;
    const int p = t & 15, rg = t >> 4;
    float m0 = 0.f, m1 = 0.f;
    for (int r = rg; r < N_; r += 32) {
        h2 z = __builtin_bit_cast(h2, xb[r * 16 + p] & 0x7FFF7FFFu);
        m0 = fmaxf(m0, (float)z.x);
        m1 = fmaxf(m1, (float)z.y);
    }
    redA[p][rg] = m0; redB[p][rg] = m1;
    const float* ub = u + (size_t)bh * N_;
    float um = -1e30f;
    for (int r = t; r < N_; r += 512) um = fmaxf(um, ub[r]);
    redu[t] = um;
    __syncthreads();
    if (t < 16) {
        float a = 0.f, b = 0.f;
        for (int g = 0; g < 32; g++) { a = fmaxf(a, redA[t][g]); b = fmaxf(b, redB[t][g]); }
        clv[2 * t] = a; clv[2 * t + 1] = b;
    }
    for (int s = 256; s > 0; s >>= 1) {
        if (t < s) redu[t] = fmaxf(redu[t], redu[t + s]);
        __syncthreads();
    }
    const float umax = redu[0];
    const unsigned int* xrb = xrh + (size_t)bh * N_ * 16;
    for (int r = t; r < N_; r += 512) {
        float s = 0.f;
        #pragma unroll
        for (int k = 0; k < 16; k++) {
            h2 z = __builtin_bit_cast(h2, xrb[r * 16 + k] & 0x7FFF7FFFu);
            s += tca[2 * k] * (clv[2 * k] + (float)z.x)
               + tca[2 * k + 1] * (clv[2 * k + 1] + (float)z.y);
        }
        bound[bh * N_ + r] = umax + s + 0.25f;
    }
}

// --- monolithic asm blocks: the whole score / PV phase of one jp lives in
// ONE asm statement, so accumulators (o[32], l) and xrp[16] are REQUIRED to
// be arch VGPRs across the full phase. Per-instruction asm (R10-R12) still
// allowed the allocator to park them in AGPRs between statements and shuttle
// v_accvgpr_read/write around every dot (~2.2x VALU inflation, the 172-198us
// plateau). Numeric order is bit-identical to R13.

// 6-instr group for dim-pair K: j0-row component aK, j1-row component bK.
#define G(K, EA, EB)                                              \
    "v_pk_add_f16 %[z0], %[a" K "], %[x" K "]\n\t"                \
    "v_pk_add_f16 %[z1], %[b" K "], %[x" K "]\n\t"                \
    "v_and_b32 %[z0], %[mk], %[z0]\n\t"                           \
    "v_and_b32 %[z1], %[mk], %[z1]\n\t"                           \
    "v_dot2_f32_f16 %[" EA "], %[z0], %[t" K "], %[" EA "]\n\t"   \
    "v_dot2_f32_f16 %[" EB "], %[z1], %[t" K "], %[" EB "]\n\t"

#define DOT(K) "v_dot2_f32_f16 %[o" K "], %[p], %[v" K "], %[o" K "]\n\t"

// Flash GATv2 attention. Lane owns target row i; 4 waves/block share the
// (bh, j-range) so j-tiles are staged in LDS (33 KB) and read as uniform
// broadcasts. Fixed-bound softmax -> j's independent. Score+PV phases are
// monolithic asm blocks (see above).
__global__ __launch_bounds__(256) void k_attn(
    const unsigned int* __restrict__ xlh,   // [bh][n][16] u32 (d-pairs)
    const unsigned int* __restrict__ xlpT,  // [bh][n/2][32] u32 (j-pairs)
    const unsigned int* __restrict__ xrh,
    const float* __restrict__ u, const float* __restrict__ bound,
    const unsigned int* __restrict__ tch,
    float* __restrict__ P, float* __restrict__ lb, int jlen)
{
    __shared__ __align__(16) uint4 s_xlh[1024];   // 256 j-rows x 4 uint4
    __shared__ __align__(16) uint4 s_xlt[1024];   // 128 jp x 8 uint4
    __shared__ float s_u[256];
    const int tid = threadIdx.x;
    const int t128 = blockIdx.x & 127, part = blockIdx.x >> 7;
    const int bh = t128 >> 3;
    const int h  = bh & (H_ - 1);
    const int row = bh * N_ + (t128 & 7) * 256 + tid;

    // wave-uniform score coefficients in SGPRs
    unsigned int tcs[16];
    #pragma unroll
    for (int k = 0; k < 16; k++)
        tcs[k] = __builtin_amdgcn_readfirstlane(tch[h * 16 + k]);

    unsigned int xrp[16];
    {
        const uint4* s = (const uint4*)(xrh + (size_t)row * 16);
        const uint4 a = s[0], b = s[1], c = s[2], d = s[3];
        xrp[0]=a.x; xrp[1]=a.y; xrp[2]=a.z; xrp[3]=a.w;
        xrp[4]=b.x; xrp[5]=b.y; xrp[6]=b.z; xrp[7]=b.w;
        xrp[8]=c.x; xrp[9]=c.y; xrp[10]=c.z; xrp[11]=c.w;
        xrp[12]=d.x; xrp[13]=d.y; xrp[14]=d.z; xrp[15]=d.w;
    }
    // +12 shift keeps p in f16 normal range; cancels in o/l.
    const float negb = 12.0f - bound[row];
    const unsigned int kOnes = 0x3C003C00u;    // (1.0h, 1.0h)
    const unsigned int kAbsMask = 0x7FFF7FFFu;

    float l = 0.f;
    float o[32];
    #pragma unroll
    for (int k = 0; k < 32; k++) o[k] = 0.f;

    const uint4* gx = (const uint4*)(xlh + (size_t)bh * N_ * 16);        // 4/row
    const uint4* gv = (const uint4*)(xlpT + (size_t)bh * (N_ / 2) * 32); // 8/jp
    const float* u_b = u + (size_t)bh * N_;

    const int jbeg = part * jlen;
    for (int jt = 0; jt < jlen; jt += 256) {
        if (jt) __syncthreads();                 // previous tile fully consumed
        const int j0 = jbeg + jt;
        #pragma unroll
        for (int k = 0; k < 4; k++)
            s_xlh[tid + 256 * k] = gx[(size_t)j0 * 4 + tid + 256 * k];
        #pragma unroll
        for (int k = 0; k < 4; k++)
            s_xlt[tid + 256 * k] = gv[(size_t)(j0 >> 1) * 8 + tid + 256 * k];
        s_u[tid] = u_b[j0 + tid];
        __syncthreads();

        for (int ljp = 0; ljp < 128; ljp++) {
            const uint4 S0 = s_xlh[8 * ljp + 0], S1 = s_xlh[8 * ljp + 1];
            const uint4 S2 = s_xlh[8 * ljp + 2], S3 = s_xlh[8 * ljp + 3];
            const uint4 S4 = s_xlh[8 * ljp + 4], S5 = s_xlh[8 * ljp + 5];
            const uint4 S6 = s_xlh[8 * ljp + 6], S7 = s_xlh[8 * ljp + 7];
            float e0 = s_u[2 * ljp] + negb, f0 = 0.f;
            float e1 = s_u[2 * ljp + 1] + negb, f1 = 0.f;
            unsigned int zz0, zz1;
            asm(G("0",  "e0", "e1") G("1",  "f0", "f1")
                G("2",  "e0", "e1") G("3",  "f0", "f1")
                G("4",  "e0", "e1") G("5",  "f0", "f1")
                G("6",  "e0", "e1") G("7",  "f0", "f1")
                G("8",  "e0", "e1") G("9",  "f0", "f1")
                G("10", "e0", "e1") G("11", "f0", "f1")
                G("12", "e0", "e1") G("13", "f0", "f1")
                G("14", "e0", "e1") G("15", "f0", "f1")
                : [e0]"+v"(e0), [f0]"+v"(f0), [e1]"+v"(e1), [f1]"+v"(f1),
                  [z0]"=&v"(zz0), [z1]"=&v"(zz1)
                : [a0]"v"(S0.x),  [a1]"v"(S0.y),  [a2]"v"(S0.z),  [a3]"v"(S0.w),
                  [a4]"v"(S1.x),  [a5]"v"(S1.y),  [a6]"v"(S1.z),  [a7]"v"(S1.w),
                  [a8]"v"(S2.x),  [a9]"v"(S2.y),  [a10]"v"(S2.z), [a11]"v"(S2.w),
                  [a12]"v"(S3.x), [a13]"v"(S3.y), [a14]"v"(S3.z), [a15]"v"(S3.w),
                  [b0]"v"(S4.x),  [b1]"v"(S4.y),  [b2]"v"(S4.z),  [b3]"v"(S4.w),
                  [b4]"v"(S5.x),  [b5]"v"(S5.y),  [b6]"v"(S5.z),  [b7]"v"(S5.w),
                  [b8]"v"(S6.x),  [b9]"v"(S6.y),  [b10]"v"(S6.z), [b11]"v"(S6.w),
                  [b12]"v"(S7.x), [b13]"v"(S7.y), [b14]"v"(S7.z), [b15]"v"(S7.w),
                  [x0]"v"(xrp[0]),   [x1]"v"(xrp[1]),   [x2]"v"(xrp[2]),   [x3]"v"(xrp[3]),
                  [x4]"v"(xrp[4]),   [x5]"v"(xrp[5]),   [x6]"v"(xrp[6]),   [x7]"v"(xrp[7]),
                  [x8]"v"(xrp[8]),   [x9]"v"(xrp[9]),   [x10]"v"(xrp[10]), [x11]"v"(xrp[11]),
                  [x12]"v"(xrp[12]), [x13]"v"(xrp[13]), [x14]"v"(xrp[14]), [x15]"v"(xrp[15]),
                  [t0]"s"(tcs[0]),   [t1]"s"(tcs[1]),   [t2]"s"(tcs[2]),   [t3]"s"(tcs[3]),
                  [t4]"s"(tcs[4]),   [t5]"s"(tcs[5]),   [t6]"s"(tcs[6]),   [t7]"s"(tcs[7]),
                  [t8]"s"(tcs[8]),   [t9]"s"(tcs[9]),   [t10]"s"(tcs[10]), [t11]"s"(tcs[11]),
                  [t12]"s"(tcs[12]), [t13]"s"(tcs[13]), [t14]"s"(tcs[14]), [t15]"s"(tcs[15]),
                  [mk]"s"(kAbsMask));
            const float p0 = EXP2(e0 + f0);
            const float p1 = EXP2(e1 + f1);
            const unsigned int p01 = __builtin_bit_cast(unsigned int,
                __builtin_amdgcn_cvt_pkrtz(p0, p1));
            const uint4 V0 = s_xlt[8 * ljp + 0], V1 = s_xlt[8 * ljp + 1];
            const uint4 V2 = s_xlt[8 * ljp + 2], V3 = s_xlt[8 * ljp + 3];
            const uint4 V4 = s_xlt[8 * ljp + 4], V5 = s_xlt[8 * ljp + 5];
            const uint4 V6 = s_xlt[8 * ljp + 6], V7 = s_xlt[8 * ljp + 7];
            asm("v_dot2_f32_f16 %[l], %[p], %[on], %[l]\n\t"
                DOT("0")  DOT("1")  DOT("2")  DOT("3")
                DOT("4")  DOT("5")  DOT("6")  DOT("7")
                DOT("8")  DOT("9")  DOT("10") DOT("11")
                DOT("12") DOT("13") DOT("14") DOT("15")
                DOT("16") DOT("17") DOT("18") DOT("19")
                DOT("20") DOT("21") DOT("22") DOT("23")
                DOT("24") DOT("25") DOT("26") DOT("27")
                DOT("28") DOT("29") DOT("30") DOT("31")
                : [l]"+v"(l),
                  [o0]"+v"(o[0]),   [o1]"+v"(o[1]),   [o2]"+v"(o[2]),   [o3]"+v"(o[3]),
                  [o4]"+v"(o[4]),   [o5]"+v"(o[5]),   [o6]"+v"(o[6]),   [o7]"+v"(o[7]),
                  [o8]"+v"(o[8]),   [o9]"+v"(o[9]),   [o10]"+v"(o[10]), [o11]"+v"(o[11]),
                  [o12]"+v"(o[12]), [o13]"+v"(o[13]), [o14]"+v"(o[14]), [o15]"+v"(o[15]),
                  [o16]"+v"(o[16]), [o17]"+v"(o[17]), [o18]"+v"(o[18]), [o19]"+v"(o[19]),
                  [o20]"+v"(o[20]), [o21]"+v"(o[21]), [o22]"+v"(o[22]), [o23]"+v"(o[23]),
                  [o24]"+v"(o[24]), [o25]"+v"(o[25]), [o26]"+v"(o[26]), [o27]"+v"(o[27]),
                  [o28]"+v"(o[28]), [o29]"+v"(o[29]), [o30]"+v"(o[30]), [o31]"+v"(o[31])
                : [p]"v"(p01), [on]"s"(kOnes),
                  [v0]"v"(V0.x),  [v1]"v"(V0.y),  [v2]"v"(V0.z),  [v3]"v"(V0.w),
                  [v4]"v"(V1.x),  [v5]"v"(V1.y),  [v6]"v"(V1.z),  [v7]"v"(V1.w),
                  [v8]"v"(V2.x),  [v9]"v"(V2.y),  [v10]"v"(V2.z), [v11]"v"(V2.w),
                  [v12]"v"(V3.x), [v13]"v"(V3.y), [v14]"v"(V3.z), [v15]"v"(V3.w),
                  [v16]"v"(V4.x), [v17]"v"(V4.y), [v18]"v"(V4.z), [v19]"v"(V4.w),
                  [v20]"v"(V5.x), [v21]"v"(V5.y), [v22]"v"(V5.z), [v23]"v"(V5.w),
                  [v24]"v"(V6.x), [v25]"v"(V6.y), [v26]"v"(V6.z), [v27]"v"(V6.w),
                  [v28]"v"(V7.x), [v29]"v"(V7.y), [v30]"v"(V7.z), [v31]"v"(V7.w));
        }
    }

    float* Pp = P + (size_t)part * M_ + (size_t)row * D_;
    #pragma unroll
    for (int k = 0; k < 8; k++) {
        v4f w;
        w.x = o[4*k]; w.y = o[4*k+1]; w.z = o[4*k+2]; w.w = o[4*k+3];
        ((v4f*)Pp)[k] = w;
    }
    lb[part * ROWS_ + row] = l;
}

// Fused: merge JS partials (shared bound -> sum(o)/sum(l)) + bias + LN(128)
// (+optional ReLU). One 64-thread block per node row (b,n).
template <int JS>
__global__ __launch_bounds__(64) void k_comb_ln(
    const float* __restrict__ P, const float* __restrict__ lb,
    const float* __restrict__ bias, const float* __restrict__ g,
    const float* __restrict__ bta, float* __restrict__ outp, int do_relu)
{
    const int row = blockIdx.x;                    // b*N+n
    const int b = row >> 11, n = row & (N_ - 1);
    const int t = threadIdx.x;
    const int c0 = t, c1 = t + 64;
    const int bh0 = b * H_ + (c0 >> 5), bh1 = b * H_ + (c1 >> 5);
    const size_t i0 = ((size_t)bh0 * N_ + n) * D_ + (c0 & 31);
    const size_t i1 = ((size_t)bh1 * N_ + n) * D_ + (c1 & 31);
    float a0 = 0.f, a1 = 0.f, L0 = 0.f, L1 = 0.f;
    #pragma unroll
    for (int s = 0; s < JS; s++) {
        a0 += P[(size_t)s * M_ + i0];
        a1 += P[(size_t)s * M_ + i1];
        L0 += lb[s * ROWS_ + bh0 * N_ + n];
        L1 += lb[s * ROWS_ + bh1 * N_ + n];
    }
    const float x0 = a0 / L0 + bias[c0];
    const float x1 = a1 / L1 + bias[c1];
    float s = x0 + x1;
    #pragma unroll
    for (int w = 1; w < 64; w <<= 1) s += __shfl_xor(s, w);
    const float mu = s * (1.f / 128.f);
    const float d0 = x0 - mu, d1 = x1 - mu;
    float q = d0 * d0 + d1 * d1;
    #pragma unroll
    for (int w = 1; w < 64; w <<= 1) q += __shfl_xor(q, w);
    const float rstd = rsqrtf(q * (1.f / 128.f) + 1e-5f);
    float y0 = d0 * rstd * g[c0] + bta[c0];
    float y1 = d1 * rstd * g[c1] + bta[c1];
    if (do_relu) { y0 = fmaxf(y0, 0.f); y1 = fmaxf(y1, 0.f); }
    outp[(size_t)row * HD_ + c0] = y0;
    outp[(size_t)row * HD_ + c1] = y1;
}

extern "C" void kernel_launch(void* const* d_in, const int* in_sizes, int n_in,
                              void* d_out, int out_size, void* d_ws, size_t ws_size,
                              hipStream_t stream) {
    const float* x    = (const float*)d_in[0];
    const float* Wl1  = (const float*)d_in[2];
    const float* bl1  = (const float*)d_in[3];
    const float* Wr1  = (const float*)d_in[4];
    const float* br1  = (const float*)d_in[5];
    const float* att1 = (const float*)d_in[6];
    const float* bias1= (const float*)d_in[7];
    const float* ln1g = (const float*)d_in[8];
    const float* ln1b = (const float*)d_in[9];
    const float* Wl2  = (const float*)d_in[10];
    const float* bl2  = (const float*)d_in[11];
    const float* Wr2  = (const float*)d_in[12];
    const float* br2  = (const float*)d_in[13];
    const float* att2 = (const float*)d_in[14];
    const float* bias2= (const float*)d_in[15];
    const float* ln2g = (const float*)d_in[16];
    const float* ln2b = (const float*)d_in[17];

    float* ws = (float*)d_ws;
    float* xl = ws;                                   // M_
    unsigned short* xlh = (unsigned short*)(xl + M_); // M_ halfs
    unsigned short* xrh = xlh + M_;                   // M_ halfs
    unsigned int* xlpT = (unsigned int*)(xrh + M_);   // M_/2 u32
    float* u     = xl + (size_t)(2.5 * M_);           // ROWS_
    float* bound = u + ROWS_;                         // ROWS_
    unsigned int* tch = (unsigned int*)(bound + ROWS_); // 64 u32

    // j-split: largest fitting. floats = 2.5M + 2R + 64 + js*(M+R) + M (h slab)
    int js = 1;
    for (int cand = 8; cand >= 1; cand >>= 1) {
        const size_t need = ((size_t)(3.5 * M_) + 2 * ROWS_ + 64
                             + (size_t)cand * (M_ + ROWS_)) * sizeof(float);
        if (ws_size >= need) { js = cand; break; }
    }
    const int jlen = N_ / js;

    float* P  = (float*)(tch + 64);        // js * M_
    float* lb = P + (size_t)js * M_;       // js * ROWS_
    float* h  = lb + (size_t)js * ROWS_;   // M_ (dedicated slab)
    float* outf = (float*)d_out;

    const int BN = B_ * N_;                // 8192
    // ---- layer 1 ----
    k_linear<<<BN / 32, 256, 0, stream>>>(x, Wl1, bl1, Wr1, br1, xl, xlh, xrh, xlpT, 32);
    k_u<<<ROWS_ / 256, 256, 0, stream>>>(xl, att1, u);
    k_bound<<<BH_, 512, 0, stream>>>((const unsigned int*)xlh, (const unsigned int*)xrh,
                                     u, att1, bound, tch);
    k_attn<<<128 * js, 256, 0, stream>>>((const unsigned int*)xlh, xlpT,
                                         (const unsigned int*)xrh, u, bound, tch, P, lb, jlen);
    if      (js == 8) k_comb_ln<8><<<BN, 64, 0, stream>>>(P, lb, bias1, ln1g, ln1b, h, 1);
    else if (js == 4) k_comb_ln<4><<<BN, 64, 0, stream>>>(P, lb, bias1, ln1g, ln1b, h, 1);
    else if (js == 2) k_comb_ln<2><<<BN, 64, 0, stream>>>(P, lb, bias1, ln1g, ln1b, h, 1);
    else              k_comb_ln<1><<<BN, 64, 0, stream>>>(P, lb, bias1, ln1g, ln1b, h, 1);
    // ---- layer 2 ----
    k_linear<<<BN / 32, 256, 0, stream>>>(h, Wl2, bl2, Wr2, br2, xl, xlh, xrh, xlpT, 128);
    k_u<<<ROWS_ / 256, 256, 0, stream>>>(xl, att2, u);
    k_bound<<<BH_, 512, 0, stream>>>((const unsigned int*)xlh, (const unsigned int*)xrh,
                                     u, att2, bound, tch);
    k_attn<<<128 * js, 256, 0, stream>>>((const unsigned int*)xlh, xlpT,
                                         (const unsigned int*)xrh, u, bound, tch, P, lb, jlen);
    if      (js == 8) k_comb_ln<8><<<BN, 64, 0, stream>>>(P, lb, bias2, ln2g, ln2b, outf, 0);
    else if (js == 4) k_comb_ln<4><<<BN, 64, 0, stream>>>(P, lb, bias2, ln2g, ln2b, outf, 0);
    else if (js == 2) k_comb_ln<2><<<BN, 64, 0, stream>>>(P, lb, bias2, ln2g, ln2b, outf, 0);
    else              k_comb_ln<1><<<BN, 64, 0, stream>>>(P, lb, bias2, ln2g, ln2b, outf, 0);
}